// Round 14
// baseline (92.584 us; speedup 1.0000x reference)
//
#include <hip/hip_runtime.h>

#define LSEQ 512
#define NB 64
#define NCHUNK 51  // 16*51 = 816 >= 512 + 3*80 + 63 = 815 steps

// lanes 1..63 <- x[lane-1]; lane 0 <- old[0] (wave_shr:1, bound_ctrl=0).
__device__ __forceinline__ float dpp_shr1(float old, float x) {
  return __int_as_float(__builtin_amdgcn_update_dpp(
      __float_as_int(old), __float_as_int(x), 0x138, 0xF, 0xF, false));
}
// lane l <- lane l+1 (wave_shl:1) — rotates injection registers.
__device__ __forceinline__ float dpp_shl1(float x) {
  return __int_as_float(__builtin_amdgcn_update_dpp(
      0, __float_as_int(x), 0x130, 0xF, 0xF, false));
}

// (d,e) pair encodes v = d - log2(e); exact softmin, log deferred to the end.
__device__ __forceinline__ void renorm(float& d, float& e) {
  const int eb = __float_as_int(e);
  const int E = (eb >> 23) - 127;
  e = __int_as_float((eb & 0x007FFFFF) | 0x3F800000);
  d -= (float)E;
}

// One 16-step chunk, 2 rows/lane, SOFTWARE-PIPELINED: iteration u executes
// d-step u (movement, min3, fma, issues 6 exp2 -> xa[u&1]) then e-step u-1
// (consumes xa[(u-1)&1], issued ~110cy earlier -> trans latency hidden; its
// serial part is mul/add only). The d-recurrence never reads e; e couples
// back only at renorm (chunk top, drained). Arithmetic identical to R13.
template <bool FULL>
__device__ __forceinline__ void chunk16(
    int cbase, const float* tg, const float2* ring2P, float2* ring2W, float p0,
    float p1, bool is_wr, int lane, float& v0d, float& v0e, float& v1d,
    float& v1e, float& r0d, float& r0e, float& tcur) {
  renorm(v0d, v0e);
  renorm(v1d, v1e);

  // injection registers: lane k (mod 16) holds step-k data for lane 0
  float tinj = tg[(cbase + (lane & 15)) & 511];
  const float2 rj = ring2P[(cbase + 1 + (lane & 15)) & 127];
  float rdinj = rj.x, reinj = rj.y;

  float vvd[16], vve[16];
  float xa[2][6];      // exp2 double-buffer (static idx after unroll)
  float d0sav[2];      // (unused value; kept for clarity of pairing)
  (void)d0sav;

#pragma unroll
  for (int u = 0; u < 16; ++u) {
    // ---- d-step u ----
    tcur = dpp_shr1(tinj, tcur);             // target'[j-1]
    const float r1d = dpp_shr1(rdinj, v1d);  // R'[i0-1][j] (d)
    if (u < 15) {
      tinj = dpp_shl1(tinj);
      rdinj = dpp_shl1(rdinj);
    }
    const float diff0 = p0 - tcur;
    const float M0 = fminf(fminf(r0d, r1d), v0d);
    xa[u & 1][0] = __builtin_amdgcn_exp2f(M0 - r0d);
    xa[u & 1][1] = __builtin_amdgcn_exp2f(M0 - r1d);
    xa[u & 1][2] = __builtin_amdgcn_exp2f(M0 - v0d);
    const float d0 = __builtin_fmaf(diff0, diff0, M0);
    const float diff1 = p1 - tcur;
    const float M1 = fminf(fminf(v0d, d0), v1d);
    xa[u & 1][3] = __builtin_amdgcn_exp2f(M1 - v0d);
    xa[u & 1][4] = __builtin_amdgcn_exp2f(M1 - d0);
    xa[u & 1][5] = __builtin_amdgcn_exp2f(M1 - v1d);
    const float d1 = __builtin_fmaf(diff1, diff1, M1);
    vvd[u] = d1;
    if (FULL) {
      v0d = d0;
      v1d = d1;
    } else {
      const int j = cbase + 1 + u - lane;
      const bool act = ((unsigned)(j - 1)) < (unsigned)LSEQ;
      v0d = act ? d0 : v0d;
      v1d = act ? d1 : v1d;
    }
    r0d = r1d;

    // ---- e-step u-1 (lagged; exp2 results from the previous iteration) ----
    if (u >= 1) {
      const int up = u - 1;
      const float r1e = dpp_shr1(reinj, v1e);
      if (up < 15) reinj = dpp_shl1(reinj);
      const float e0 = (xa[up & 1][0] * r0e + xa[up & 1][1] * r1e) +
                       xa[up & 1][2] * v0e;
      const float e1 = (xa[up & 1][3] * v0e + xa[up & 1][4] * e0) +
                       xa[up & 1][5] * v1e;
      vve[up] = e1;
      if (FULL) {
        v0e = e0;
        v1e = e1;
      } else {
        const int j = cbase + 1 + up - lane;
        const bool act = ((unsigned)(j - 1)) < (unsigned)LSEQ;
        v0e = act ? e0 : v0e;
        v1e = act ? e1 : v1e;
      }
      r0e = r1e;
    }
  }
  {  // ---- drain e-step 15 ----
    const float r1e = dpp_shr1(reinj, v1e);
    const float e0 = (xa[1][0] * r0e + xa[1][1] * r1e) + xa[1][2] * v0e;
    const float e1 = (xa[1][3] * v0e + xa[1][4] * e0) + xa[1][5] * v1e;
    vve[15] = e1;
    if (FULL) {
      v0e = e0;
      v1e = e1;
    } else {
      const int j = cbase + 16 - lane;
      const bool act = ((unsigned)(j - 1)) < (unsigned)LSEQ;
      v0e = act ? e0 : v0e;
      v1e = act ? e1 : v1e;
    }
    r0e = r1e;
  }

  if (is_wr) {  // lane 63 publishes row 128(w+1) = its i1
    const int j0 = cbase - 62;
#pragma unroll
    for (int k = 0; k < 16; ++k) {
      if (FULL || (((unsigned)(j0 + k - 1)) < (unsigned)LSEQ))
        ring2W[(j0 + k) & 127] = make_float2(vvd[k], vve[k]);
    }
  }
}

// Soft-DTW banded wavefront, one block per batch, 4 waves x 64 lanes x 2 rows.
// Lane l of wave w owns rows 128w+2l+1, +2; column j = s - 80w - l at step s.
// Ring (lag=80): entry col J read by wave w at top of chunk c was written by
// wave w-1 in its chunk c-1, burst (post-drain) before the top-of-c barrier.
// During wave w's chunk-c body, wave w-1 writes only cols +18..+33 past the
// read window — disjoint mod 128.
__global__ __launch_bounds__(256) void dtw_band(
    const float* __restrict__ pred, const float* __restrict__ target,
    float* __restrict__ part) {
  const int b = blockIdx.x;
  const int tid = threadIdx.x;  // 0..255
  const int w = tid >> 6;
  const int lane = tid & 63;
  const bool is_wr = (lane == 63) && (w < 3);

  __shared__ float tg[LSEQ];
  __shared__ float2 rings2[4][128];  // rows 0..2: interfaces; row 3: INF dummy

  const float SC = 3.79828146f;  // sqrt(C1), C1 = (1/g)*log2(e), g = 0.1
  const float2 pp = ((const float2*)(pred + b * LSEQ))[tid];
  const float p0 = pp.x * SC, p1 = pp.y * SC;  // rows 2*tid+1, 2*tid+2
  const float2 tt = ((const float2*)(target + b * LSEQ))[tid];
  ((float2*)tg)[tid] = make_float2(tt.x * SC, tt.y * SC);
  ((float2*)rings2)[tid] = make_float2(INFINITY, 1.0f);
  ((float2*)rings2)[tid + 256] = make_float2(INFINITY, 1.0f);

  const int lag = w * 80;
  const int cw0 = 5 * w;  // wave-active chunks: [cw0, cw0+35]
  const float2* __restrict__ ring2P = rings2[w == 0 ? 3 : w - 1];
  float2* __restrict__ ring2W = rings2[w];

  float v0d = INFINITY, v0e = 1.0f;          // R'[i0][j-1]
  float v1d = INFINITY, v1e = 1.0f;          // R'[i1][j-1]
  float r0d = (tid == 0) ? 0.0f : INFINITY;  // R'[i0-1][j-1]; seed R'[0][0]
  float r0e = 1.0f;
  float tcur = 0.0f;

  for (int c = 0; c < NCHUNK; ++c) {
    __syncthreads();  // top of chunk c (also orders init writes at c=0)
    if (c < cw0 || c > cw0 + 35) continue;  // wave-uniform
    const int cbase = 16 * c - lag;
    if (c >= cw0 + 4 && c <= cw0 + 31)
      chunk16<true>(cbase, tg, ring2P, ring2W, p0, p1, is_wr, lane, v0d, v0e,
                    v1d, v1e, r0d, r0e, tcur);
    else
      chunk16<false>(cbase, tg, ring2P, ring2W, p0, p1, is_wr, lane, v0d, v0e,
                     v1d, v1e, r0d, r0e, tcur);
  }

  if (tid == 255)  // row 512 = wave 3 lane 63 i1; unscale by 1/C1 = g*ln2
    part[b] = (v1d - __builtin_amdgcn_logf(v1e)) * 0.069314718f;
}

__global__ void dtw_reduce(const float* __restrict__ part,
                           float* __restrict__ out) {
  float v = part[threadIdx.x];
#pragma unroll
  for (int o = 32; o > 0; o >>= 1) v += __shfl_down(v, o);
  if (threadIdx.x == 0) out[0] = v * (1.0f / NB);
}

extern "C" void kernel_launch(void* const* d_in, const int* in_sizes, int n_in,
                              void* d_out, int out_size, void* d_ws,
                              size_t ws_size, hipStream_t stream) {
  const float* pred = (const float*)d_in[0];
  const float* target = (const float*)d_in[1];
  float* part = (float*)d_ws;

  dtw_band<<<NB, 256, 0, stream>>>(pred, target, part);
  dtw_reduce<<<1, 64, 0, stream>>>(part, (float*)d_out);
}